// Round 3
// baseline (430.999 us; speedup 1.0000x reference)
//
#include <hip/hip_runtime.h>

// out[t, d] = x[t, d] * gain[d]
// gain[d] = sum_n cos(n * OMEGA * DT - eps[n,d] * DT)
// eps[n,d] = floquet_energies[n,d] * (1 + 0.1 * drive_weights[n])
// coupling_matrix unused.

#define F_DT 0.01f
#define F_OMEGA 1.0f

typedef float floatx4 __attribute__((ext_vector_type(4)));  // clang vector: nt-builtin-compatible

__global__ void gain_kernel(const float* __restrict__ fe,
                            const float* __restrict__ dw,
                            float* __restrict__ gain, int M, int D) {
    int d = blockIdx.x * blockDim.x + threadIdx.x;
    if (d >= D) return;
    float g = 0.0f;
    for (int n = 0; n < M; ++n) {
        float eps = fe[(long long)n * D + d] * (1.0f + 0.1f * dw[n]);
        g += cosf((float)n * (F_OMEGA * F_DT) - eps * F_DT);
    }
    gain[d] = g;
}

// Streaming elementwise scale: nontemporal x/out (touched once), cached gain.
__global__ void __launch_bounds__(256) scale_kernel(
        const floatx4* __restrict__ x,
        const floatx4* __restrict__ gain4,
        floatx4* __restrict__ out,
        long long n4, unsigned int DqMask) {
    long long stride = (long long)gridDim.x * blockDim.x;
    for (long long i = (long long)blockIdx.x * blockDim.x + threadIdx.x;
         i < n4; i += stride) {
        floatx4 xv = __builtin_nontemporal_load(&x[i]);
        floatx4 gv = gain4[(unsigned int)i & DqMask];  // Dq is pow2 (1024)
        floatx4 o = xv * gv;
        __builtin_nontemporal_store(o, &out[i]);
    }
}

// Fallback for non-pow2 D/4 (not expected for this problem, kept for safety).
__global__ void __launch_bounds__(256) scale_kernel_mod(
        const floatx4* __restrict__ x,
        const floatx4* __restrict__ gain4,
        floatx4* __restrict__ out,
        long long n4, int Dq) {
    long long stride = (long long)gridDim.x * blockDim.x;
    for (long long i = (long long)blockIdx.x * blockDim.x + threadIdx.x;
         i < n4; i += stride) {
        floatx4 xv = __builtin_nontemporal_load(&x[i]);
        floatx4 gv = gain4[i % Dq];
        floatx4 o = xv * gv;
        __builtin_nontemporal_store(o, &out[i]);
    }
}

extern "C" void kernel_launch(void* const* d_in, const int* in_sizes, int n_in,
                              void* d_out, int out_size, void* d_ws, size_t ws_size,
                              hipStream_t stream) {
    const float* x  = (const float*)d_in[0];
    const float* fe = (const float*)d_in[1];
    const float* dw = (const float*)d_in[2];
    // d_in[3] = coupling_matrix, unused by the forward

    float* out  = (float*)d_out;
    float* gain = (float*)d_ws;   // D floats of scratch

    int M = in_sizes[2];                 // drive_weights: [M]
    int D = in_sizes[1] / M;             // floquet_energies: [M, D]
    long long n = (long long)in_sizes[0];

    // 1) gain[d], one thread per d
    {
        int threads = 256;
        int blocks = (D + threads - 1) / threads;
        gain_kernel<<<blocks, threads, 0, stream>>>(fe, dw, gain, M, D);
    }

    // 2) elementwise scale, float4-vectorized, grid-stride (~4 iters/thread)
    {
        long long n4 = n / 4;
        int Dq = D / 4;
        int threads = 256;
        int blocks = 16384;  // 256 CUs x 64 blocks; 4 floatx4/thread at n4=16M
        long long needed = (n4 + threads - 1) / threads;
        if ((long long)blocks > needed) blocks = (int)needed;
        if ((Dq & (Dq - 1)) == 0) {
            scale_kernel<<<blocks, threads, 0, stream>>>(
                (const floatx4*)x, (const floatx4*)gain, (floatx4*)out,
                n4, (unsigned int)(Dq - 1));
        } else {
            scale_kernel_mod<<<blocks, threads, 0, stream>>>(
                (const floatx4*)x, (const floatx4*)gain, (floatx4*)out, n4, Dq);
        }
    }
}